// Round 1
// baseline (219.458 us; speedup 1.0000x reference)
//
#include <hip/hip_runtime.h>

#define NROWS 8192
#define DH 128
#define BK 32
#define NWAVES 4
#define BQ_WG 128   // 4 waves * 32 q rows

typedef float f32x16 __attribute__((ext_vector_type(16)));
typedef float f32x4  __attribute__((ext_vector_type(4)));
typedef short s16x8  __attribute__((ext_vector_type(8)));

#define MFMA(a, b, c) __builtin_amdgcn_mfma_f32_32x32x16_bf16(a, b, c, 0, 0, 0)
#define EXP2F(x) __builtin_amdgcn_exp2f(x)

// fp32 -> bf16 bits (RNE)
__device__ __forceinline__ short f2bf(float x) {
    unsigned u = __float_as_uint(x);
    unsigned r = (u + 0x7fffu + ((u >> 16) & 1u)) >> 16;
    return (short)r;
}
__device__ __forceinline__ float bf2f(short s) {
    return __uint_as_float(((unsigned)(unsigned short)s) << 16);
}

// log2-domain combined scale: sqrt(8192) * log2(e)
#define CSC 130.577849f

__global__ __launch_bounds__(256, 2) void fa_partial(
    const float* __restrict__ Qm, const float* __restrict__ KV,
    float* __restrict__ Opart, float* __restrict__ mlbuf, int ksplit_rows)
{
    __shared__ __align__(16) short kh[32 * 128];          // K tile hi (bf16), swizzled
    __shared__ __align__(16) short kl[32 * 128];          // K tile lo
    __shared__ __align__(16) short vt[128 * 32];          // V tile transposed [d][k], swizzled
    __shared__ __align__(16) short pb[NWAVES][32 * 64];   // per-wave P[q][k], rows padded to 128B

    const int tid  = threadIdx.x;
    const int wid  = tid >> 6;
    const int lane = tid & 63;
    const int q32  = lane & 31;
    const int g    = lane >> 5;
    const int qb   = blockIdx.x;
    const int sp   = blockIdx.y;

    // ---- Q fragments: 32 rows per wave, pre-scaled by CSC, split hi/lo bf16.
    // B-operand layout for mfma_32x32x16: n = lane&31 (q), kdim = (lane>>5)*8 + j (d)
    s16x8 qh[8], ql[8];
    {
        const float* qrow = Qm + ((size_t)(qb * BQ_WG + wid * 32 + q32)) * DH + g * 8;
        #pragma unroll
        for (int c = 0; c < 8; ++c) {
            const float* p = qrow + c * 16;
            f32x4 v0 = *(const f32x4*)(p);
            f32x4 v1 = *(const f32x4*)(p + 4);
            #pragma unroll
            for (int j = 0; j < 8; ++j) {
                float x = ((j < 4) ? v0[j] : v1[j - 4]) * CSC;
                short h = f2bf(x);
                qh[c][j] = h;
                ql[c][j] = f2bf(x - bf2f(h));
            }
        }
    }

    f32x16 oacc[4];
    #pragma unroll
    for (int b = 0; b < 4; ++b)
        #pragma unroll
        for (int i = 0; i < 16; ++i) oacc[b][i] = 0.0f;
    float mrun = -INFINITY;
    float lrun = 0.0f;

    const int row0   = sp * ksplit_rows;
    const int ntiles = ksplit_rows / BK;

    for (int t = 0; t < ntiles; ++t) {
        const float* kt = KV + ((size_t)(row0 + t * BK)) * DH;
        __syncthreads();   // B1: previous tile fully consumed

        // ---- stage K tile (32x128 fp32) as bf16 hi/lo into swizzled LDS
        {
            const int r  = tid >> 3;            // 0..31
            const int d0 = (tid & 7) << 4;      // 0,16,..,112
            const float* src = kt + r * DH + d0;
            f32x4 a0 = *(const f32x4*)(src);
            f32x4 a1 = *(const f32x4*)(src + 4);
            f32x4 a2 = *(const f32x4*)(src + 8);
            f32x4 a3 = *(const f32x4*)(src + 12);
            s16x8 h0, h1, l0, l1;
            #pragma unroll
            for (int j = 0; j < 4; ++j) {
                { float x = a0[j]; short h = f2bf(x); h0[j]     = h; l0[j]     = f2bf(x - bf2f(h)); }
                { float x = a1[j]; short h = f2bf(x); h0[j + 4] = h; l0[j + 4] = f2bf(x - bf2f(h)); }
                { float x = a2[j]; short h = f2bf(x); h1[j]     = h; l1[j]     = f2bf(x - bf2f(h)); }
                { float x = a3[j]; short h = f2bf(x); h1[j + 4] = h; l1[j + 4] = f2bf(x - bf2f(h)); }
            }
            const int base = r * 128 + d0;
            const int swz  = (r & 7) << 3;     // XOR 16B granules (short units)
            *(s16x8*)&kh[(base    ) ^ swz] = h0;
            *(s16x8*)&kh[(base + 8) ^ swz] = h1;
            *(s16x8*)&kl[(base    ) ^ swz] = l0;
            *(s16x8*)&kl[(base + 8) ^ swz] = l1;
        }
        __syncthreads();   // B2: K tile visible

        // ---- build transposed V (= K hi) tile: vt[d][k], swizzled
        {
            const int pr = tid & 15;       // row pair 0..15
            const int c8 = tid >> 4;       // 0..15 -> d0 = c8*8
            const int r0 = pr * 2;
            const int i0 = (r0 * 128 + c8 * 8) ^ ((r0 & 7) << 3);
            const int i1 = ((r0 + 1) * 128 + c8 * 8) ^ (((r0 + 1) & 7) << 3);
            s16x8 va = *(const s16x8*)&kh[i0];
            s16x8 vb = *(const s16x8*)&kh[i1];
            #pragma unroll
            for (int i = 0; i < 8; ++i) {
                int d = c8 * 8 + i;
                unsigned w = ((unsigned)(unsigned short)vb[i] << 16) | (unsigned short)va[i];
                int idx = (d * 32 + r0) ^ (((d >> 1) & 3) << 3);
                *(unsigned*)&vt[idx] = w;
            }
        }

        // ---- QK^T (swapped: S^T = K * Q^T), split-precision 3-MFMA
        // A-operand: m = lane&31 (k-row), kdim = (lane>>5)*8 + j (d)
        f32x16 s;
        #pragma unroll
        for (int i = 0; i < 16; ++i) s[i] = 0.0f;
        #pragma unroll
        for (int c = 0; c < 8; ++c) {
            const int ia = (q32 * 128 + c * 16 + g * 8) ^ ((q32 & 7) << 3);
            s16x8 ah = *(const s16x8*)&kh[ia];
            s16x8 al = *(const s16x8*)&kl[ia];
            s = MFMA(ah, ql[c], s);   // hi*lo
            s = MFMA(al, qh[c], s);   // lo*hi
            s = MFMA(ah, qh[c], s);   // hi*hi last
        }

        // ---- online softmax; lane owns q = q32 (16 of 32 k's; partner lane^32 has rest)
        float tmax = s[0];
        #pragma unroll
        for (int i = 1; i < 16; ++i) tmax = fmaxf(tmax, s[i]);
        tmax = fmaxf(tmax, __shfl_xor(tmax, 32));
        const float mnew  = fmaxf(mrun, tmax);
        const float alpha = EXP2F(mrun - mnew);
        float psum = 0.0f;
        #pragma unroll
        for (int i = 0; i < 16; ++i) { s[i] = EXP2F(s[i] - mnew); psum += s[i]; }
        psum += __shfl_xor(psum, 32);
        lrun = lrun * alpha + psum;
        if (__any(mnew > mrun)) {   // rescale O only when some row found a new max
            #pragma unroll
            for (int rI = 0; rI < 16; ++rI) {
                int qr = (rI & 3) + 8 * (rI >> 2) + 4 * g;   // C/D row map
                float ar = __shfl(alpha, qr);
                #pragma unroll
                for (int b = 0; b < 4; ++b) oacc[b][rI] *= ar;
            }
        }
        mrun = mnew;

        // ---- pack P to bf16, per-wave LDS P[q][k] (row 64 shorts = 128B), swizzled
        {
            short* pw = pb[wid];
            #pragma unroll
            for (int pr2 = 0; pr2 < 8; ++pr2) {
                int rI = pr2 * 2;
                int k  = (rI & 3) + 8 * (rI >> 2) + 4 * g;   // k, k+1 adjacent
                unsigned w = ((unsigned)(unsigned short)f2bf(s[rI + 1]) << 16) |
                             (unsigned short)f2bf(s[rI]);
                int idx = (q32 * 64 + k) ^ ((q32 & 7) << 3);
                *(unsigned*)&pw[idx] = w;
            }
        }
        __syncthreads();   // B3: vt complete (and P drained)

        // ---- PV: O += P * V   (A = P[q][k], B = V[k][d] via vt)
        #pragma unroll
        for (int c2 = 0; c2 < 2; ++c2) {
            const int ip = (q32 * 64 + c2 * 16 + g * 8) ^ ((q32 & 7) << 3);
            s16x8 pa = *(const s16x8*)&pb[wid][ip];
            #pragma unroll
            for (int b = 0; b < 4; ++b) {
                int d  = b * 32 + q32;
                int iv = (d * 32 + c2 * 16 + g * 8) ^ (((d >> 1) & 3) << 3);
                s16x8 vv = *(const s16x8*)&vt[iv];
                oacc[b] = MFMA(pa, vv, oacc[b]);
            }
        }
    }

    // ---- write partials (unnormalized O, plus per-row m,l)
    {
        float* op = Opart + ((size_t)sp * NROWS + qb * BQ_WG + wid * 32) * DH;
        #pragma unroll
        for (int b = 0; b < 4; ++b)
            #pragma unroll
            for (int rI = 0; rI < 16; ++rI) {
                int qr = (rI & 3) + 8 * (rI >> 2) + 4 * g;
                op[qr * DH + b * 32 + q32] = oacc[b][rI];
            }
        if (lane < 32) {
            float2* mlp = (float2*)mlbuf;
            mlp[(size_t)sp * NROWS + qb * BQ_WG + wid * 32 + q32] = make_float2(mrun, lrun);
        }
    }
}

__global__ void fa_merge(const float* __restrict__ Opart,
                         const float* __restrict__ mlbuf,
                         float* __restrict__ out, int nsplit)
{
    int idx = blockIdx.x * 256 + threadIdx.x;   // over NROWS*DH
    int q   = idx >> 7;
    const float2* mlp = (const float2*)mlbuf;
    float2 mls[8];
    float M = -INFINITY;
    for (int s2 = 0; s2 < nsplit; ++s2) {
        mls[s2] = mlp[(size_t)s2 * NROWS + q];
        M = fmaxf(M, mls[s2].x);
    }
    float L = 0.0f, acc = 0.0f;
    for (int s2 = 0; s2 < nsplit; ++s2) {
        float w = EXP2F(mls[s2].x - M);
        L   += w * mls[s2].y;
        acc += w * Opart[(size_t)s2 * NROWS * DH + idx];
    }
    out[idx] = acc / L;
}

extern "C" void kernel_launch(void* const* d_in, const int* in_sizes, int n_in,
                              void* d_out, int out_size, void* d_ws, size_t ws_size,
                              hipStream_t stream)
{
    const float* p1 = (const float*)d_in[0];
    const float* p2 = (const float*)d_in[1];
    float* out = (float*)d_out;

    const size_t per_split = (size_t)NROWS * DH * sizeof(float) + (size_t)NROWS * 2 * sizeof(float);
    int nsplit = 1;
    const int cand[3] = {8, 4, 2};
    for (int i = 0; i < 3; ++i) {
        if ((size_t)cand[i] * per_split <= ws_size) { nsplit = cand[i]; break; }
    }

    float* Opart;
    float* mlbuf;
    if (per_split > ws_size) {
        // tiny-ws fallback: single split, partials live directly in d_out
        nsplit = 1;
        Opart  = out;
        mlbuf  = (float*)d_ws;
    } else {
        Opart = (float*)d_ws;
        mlbuf = (float*)d_ws + (size_t)nsplit * NROWS * DH;
    }

    const int krows = NROWS / nsplit;
    dim3 grid1(NROWS / BQ_WG, nsplit);
    fa_partial<<<grid1, 256, 0, stream>>>(p1, p2, Opart, mlbuf, krows);
    fa_merge<<<(NROWS * DH) / 256, 256, 0, stream>>>(Opart, mlbuf, out, nsplit);
}

// Round 3
// 156.315 us; speedup vs baseline: 1.4039x; 1.4039x over previous
//
#include <hip/hip_runtime.h>

#define NROWS 8192
#define DH 128
#define NTILES 256            // NROWS / 32
#define NWAVES 4
#define BQ_WG 128             // 4 waves * 32 q rows
#define TILE_SHORTS 12288     // 24KB per K tile: kh 4096 + kl 4096 + vt 4096 shorts

typedef float f32x16 __attribute__((ext_vector_type(16)));
typedef float f32x4  __attribute__((ext_vector_type(4)));
typedef short s16x8  __attribute__((ext_vector_type(8)));

#define MFMA(a, b, c) __builtin_amdgcn_mfma_f32_32x32x16_bf16(a, b, c, 0, 0, 0)
#define EXP2F(x) __builtin_amdgcn_exp2f(x)

// fp32 -> bf16 bits (RNE)
__device__ __forceinline__ short f2bf(float x) {
    unsigned u = __float_as_uint(x);
    unsigned r = (u + 0x7fffu + ((u >> 16) & 1u)) >> 16;
    return (short)r;
}
__device__ __forceinline__ float bf2f(short s) {
    return __uint_as_float(((unsigned)(unsigned short)s) << 16);
}

// log2-domain combined scale: sqrt(8192) * log2(e)
#define CSC 130.577849f

__device__ __forceinline__ void gload16(const short* g, short* l) {
    __builtin_amdgcn_global_load_lds(
        (const __attribute__((address_space(1))) unsigned*)g,
        (__attribute__((address_space(3))) unsigned*)l, 16, 0, 0);
}

// ---------------------------------------------------------------------------
// prep: convert p2 (fp32) into per-tile swizzled LDS images in ws:
//   per 32-row tile t: [kh 8KB][kl 8KB][vt 8KB] contiguous (24KB)
//   kh/kl: idx = (r*128 + d) ^ ((r&7)<<3)           (short units)
//   vt   : idx = (d*32 + k) ^ (((d>>1)&3)<<3)       (short units, word writes)
// ---------------------------------------------------------------------------
__global__ __launch_bounds__(256) void prep(const float* __restrict__ KV,
                                            short* __restrict__ kws)
{
    const int t = blockIdx.x;
    const int tid = threadIdx.x;
    short* kh = kws + (size_t)t * TILE_SHORTS;
    short* kl = kh + 4096;
    short* vt = kh + 8192;

    // ---- Kh / Kl (each thread: one row-slice of 16 floats)
    {
        const int r  = tid >> 3;            // 0..31
        const int d0 = (tid & 7) << 4;      // 0,16,..,112
        const float* src = KV + ((size_t)(t * 32 + r)) * DH + d0;
        f32x4 a0 = *(const f32x4*)(src);
        f32x4 a1 = *(const f32x4*)(src + 4);
        f32x4 a2 = *(const f32x4*)(src + 8);
        f32x4 a3 = *(const f32x4*)(src + 12);
        s16x8 h0, h1, l0, l1;
        #pragma unroll
        for (int j = 0; j < 4; ++j) {
            { float x = a0[j]; short h = f2bf(x); h0[j]     = h; l0[j]     = f2bf(x - bf2f(h)); }
            { float x = a1[j]; short h = f2bf(x); h0[j + 4] = h; l0[j + 4] = f2bf(x - bf2f(h)); }
            { float x = a2[j]; short h = f2bf(x); h1[j]     = h; l1[j]     = f2bf(x - bf2f(h)); }
            { float x = a3[j]; short h = f2bf(x); h1[j + 4] = h; l1[j + 4] = f2bf(x - bf2f(h)); }
        }
        const int base = r * 128 + d0;
        const int swz  = (r & 7) << 3;
        *(s16x8*)&kh[(base    ) ^ swz] = h0;
        *(s16x8*)&kh[(base + 8) ^ swz] = h1;
        *(s16x8*)&kl[(base    ) ^ swz] = l0;
        *(s16x8*)&kl[(base + 8) ^ swz] = l1;
    }

    // ---- Vt (transposed bf16-hi of the same tile)
    {
        const int pr = tid & 15;        // row pair
        const int c8 = tid >> 4;        // d block
        const int r0 = pr * 2;
        const float* sa = KV + ((size_t)(t * 32 + r0)) * DH + c8 * 8;
        const float* sb = sa + DH;
        f32x4 a0 = *(const f32x4*)(sa);
        f32x4 a1 = *(const f32x4*)(sa + 4);
        f32x4 b0 = *(const f32x4*)(sb);
        f32x4 b1 = *(const f32x4*)(sb + 4);
        #pragma unroll
        for (int i = 0; i < 8; ++i) {
            int d = c8 * 8 + i;
            float xa = (i < 4) ? a0[i] : a1[i - 4];
            float xb = (i < 4) ? b0[i] : b1[i - 4];
            unsigned w = ((unsigned)(unsigned short)f2bf(xb) << 16) |
                         (unsigned short)f2bf(xa);
            int idx = (d * 32 + r0) ^ (((d >> 1) & 3) << 3);
            *(unsigned*)&vt[idx] = w;
        }
    }
}

// ---------------------------------------------------------------------------
// fa_partial: flash partial over one K-split, double-buffered LDS staging
// ---------------------------------------------------------------------------
__global__ __launch_bounds__(256, 2) void fa_partial(
    const float* __restrict__ Qm, const short* __restrict__ kws,
    float* __restrict__ Opart, float* __restrict__ mlbuf, int tiles_per_split)
{
    __shared__ __align__(16) short buf[2][TILE_SHORTS];   // 2 x 24KB
    __shared__ __align__(16) short pb[NWAVES][32 * 64];   // per-wave P, 16KB

    const int tid  = threadIdx.x;
    const int wid  = tid >> 6;
    const int lane = tid & 63;
    const int q32  = lane & 31;
    const int g    = lane >> 5;
    const int qb   = blockIdx.x;
    const int sp   = blockIdx.y;
    const int tile0 = sp * tiles_per_split;

    // ---- Q fragments: pre-scaled by CSC, split hi/lo bf16 (held in regs)
    s16x8 qh[8], ql[8];
    {
        const float* qrow = Qm + ((size_t)(qb * BQ_WG + wid * 32 + q32)) * DH + g * 8;
        #pragma unroll
        for (int c = 0; c < 8; ++c) {
            const float* p = qrow + c * 16;
            f32x4 v0 = *(const f32x4*)(p);
            f32x4 v1 = *(const f32x4*)(p + 4);
            #pragma unroll
            for (int j = 0; j < 8; ++j) {
                float x = ((j < 4) ? v0[j] : v1[j - 4]) * CSC;
                short h = f2bf(x);
                qh[c][j] = h;
                ql[c][j] = f2bf(x - bf2f(h));
            }
        }
    }

    f32x16 oacc[4];
    #pragma unroll
    for (int b = 0; b < 4; ++b)
        #pragma unroll
        for (int i = 0; i < 16; ++i) oacc[b][i] = 0.0f;
    float mrun = -INFINITY;
    float lrun = 0.0f;

#define STAGE(bb, tt) do {                                              \
        const short* gs_ = kws + (size_t)(tt) * TILE_SHORTS + tid * 8;  \
        short* ld_ = &buf[bb][tid * 8];                                 \
        _Pragma("unroll")                                               \
        for (int ch_ = 0; ch_ < 6; ++ch_)                               \
            gload16(gs_ + ch_ * 2048, ld_ + ch_ * 2048);                \
    } while (0)

    int cur = 0;
    STAGE(0, tile0);

    for (int t = 0; t < tiles_per_split; ++t) {
        __syncthreads();   // drains vmcnt (tile t ready) + all waves done with buf[cur^1]
        if (t + 1 < tiles_per_split) STAGE(cur ^ 1, tile0 + t + 1);

        const short* kh = &buf[cur][0];
        const short* kl = &buf[cur][4096];
        const short* vt = &buf[cur][8192];

        // ---- QK^T (swapped: S^T = K * Q^T), split-precision 3-MFMA
        f32x16 s;
        #pragma unroll
        for (int i = 0; i < 16; ++i) s[i] = 0.0f;
        #pragma unroll
        for (int c = 0; c < 8; ++c) {
            const int ia = (q32 * 128 + c * 16 + g * 8) ^ ((q32 & 7) << 3);
            s16x8 ah = *(const s16x8*)&kh[ia];
            s16x8 al = *(const s16x8*)&kl[ia];
            s = MFMA(ah, ql[c], s);   // hi*lo
            s = MFMA(al, qh[c], s);   // lo*hi
            s = MFMA(ah, qh[c], s);   // hi*hi
        }

        // ---- online softmax (lane owns q=q32; partner lane^32 has other 16 k's)
        float tmax = s[0];
        #pragma unroll
        for (int i = 1; i < 16; ++i) tmax = fmaxf(tmax, s[i]);
        tmax = fmaxf(tmax, __shfl_xor(tmax, 32));
        const float mnew  = fmaxf(mrun, tmax);
        const float alpha = EXP2F(mrun - mnew);
        float psum = 0.0f;
        #pragma unroll
        for (int i = 0; i < 16; ++i) { s[i] = EXP2F(s[i] - mnew); psum += s[i]; }
        psum += __shfl_xor(psum, 32);
        lrun = lrun * alpha + psum;
        if (__any(mnew > mrun)) {
            #pragma unroll
            for (int rI = 0; rI < 16; ++rI) {
                int qr = (rI & 3) + 8 * (rI >> 2) + 4 * g;
                float ar = __shfl(alpha, qr);
                #pragma unroll
                for (int b = 0; b < 4; ++b) oacc[b][rI] *= ar;
            }
        }
        mrun = mnew;

        // ---- pack P to bf16, per-wave LDS P[q][k] (swizzled)
        {
            short* pw = pb[wid];
            #pragma unroll
            for (int pr2 = 0; pr2 < 8; ++pr2) {
                int rI = pr2 * 2;
                int k  = (rI & 3) + 8 * (rI >> 2) + 4 * g;
                unsigned w = ((unsigned)(unsigned short)f2bf(s[rI + 1]) << 16) |
                             (unsigned short)f2bf(s[rI]);
                int idx = (q32 * 64 + k) ^ ((q32 & 7) << 3);
                *(unsigned*)&pw[idx] = w;
            }
        }

        // ---- PV: O += P * V
        #pragma unroll
        for (int c2 = 0; c2 < 2; ++c2) {
            const int ip = (q32 * 64 + c2 * 16 + g * 8) ^ ((q32 & 7) << 3);
            s16x8 pa = *(const s16x8*)&pb[wid][ip];
            #pragma unroll
            for (int b = 0; b < 4; ++b) {
                int d  = b * 32 + q32;
                int iv = (d * 32 + c2 * 16 + g * 8) ^ (((d >> 1) & 3) << 3);
                s16x8 vv = *(const s16x8*)&vt[iv];
                oacc[b] = MFMA(pa, vv, oacc[b]);
            }
        }
        cur ^= 1;
    }
#undef STAGE

    // ---- write partials
    {
        float* op = Opart + ((size_t)sp * NROWS + qb * BQ_WG + wid * 32) * DH;
        #pragma unroll
        for (int b = 0; b < 4; ++b)
            #pragma unroll
            for (int rI = 0; rI < 16; ++rI) {
                int qr = (rI & 3) + 8 * (rI >> 2) + 4 * g;
                op[qr * DH + b * 32 + q32] = oacc[b][rI];
            }
        if (lane < 32) {
            float2* mlp = (float2*)mlbuf;
            mlp[(size_t)sp * NROWS + qb * BQ_WG + wid * 32 + q32] = make_float2(mrun, lrun);
        }
    }
}

// ---------------------------------------------------------------------------
// merge: compile-time NS => registers, no scratch
// ---------------------------------------------------------------------------
template <int NS>
__global__ __launch_bounds__(256) void fa_merge(const float* __restrict__ Opart,
                                               const float* __restrict__ mlbuf,
                                               float* __restrict__ out)
{
    int idx = blockIdx.x * 256 + threadIdx.x;
    int q   = idx >> 7;
    const float2* mlp = (const float2*)mlbuf;
    float2 mls[NS];
    float M = -INFINITY;
    #pragma unroll
    for (int s2 = 0; s2 < NS; ++s2) {
        mls[s2] = mlp[(size_t)s2 * NROWS + q];
        M = fmaxf(M, mls[s2].x);
    }
    float L = 0.0f, acc = 0.0f;
    #pragma unroll
    for (int s2 = 0; s2 < NS; ++s2) {
        float w = EXP2F(mls[s2].x - M);
        L   += w * mls[s2].y;
        acc += w * Opart[(size_t)s2 * NROWS * DH + idx];
    }
    out[idx] = acc / L;
}

extern "C" void kernel_launch(void* const* d_in, const int* in_sizes, int n_in,
                              void* d_out, int out_size, void* d_ws, size_t ws_size,
                              hipStream_t stream)
{
    const float* p1 = (const float*)d_in[0];
    const float* p2 = (const float*)d_in[1];
    float* out = (float*)d_out;

    const size_t kws_bytes  = (size_t)NTILES * TILE_SHORTS * sizeof(short);  // 6 MB
    const size_t per_split  = (size_t)NROWS * DH * sizeof(float)             // O partial
                            + (size_t)NROWS * 2 * sizeof(float);             // m,l

    int nsplit = 1;
    const int cand[3] = {8, 4, 2};
    for (int i = 0; i < 3; ++i)
        if (kws_bytes + (size_t)cand[i] * per_split <= ws_size) { nsplit = cand[i]; break; }

    short* kws = (short*)d_ws;
    float* Opart;
    float* mlbuf;
    if (nsplit == 1) {
        // minimal-ws fallback: partials straight into d_out
        Opart = out;
        mlbuf = (float*)((char*)d_ws + kws_bytes);
    } else {
        Opart = (float*)((char*)d_ws + kws_bytes);
        mlbuf = Opart + (size_t)nsplit * NROWS * DH;
    }

    prep<<<NTILES, 256, 0, stream>>>(p2, kws);

    dim3 grid1(NROWS / BQ_WG, nsplit);
    fa_partial<<<grid1, 256, 0, stream>>>(p1, kws, Opart, mlbuf, NTILES / nsplit);

    const int mgrid = (NROWS * DH) / 256;
    if (nsplit == 8)      fa_merge<8><<<mgrid, 256, 0, stream>>>(Opart, mlbuf, out);
    else if (nsplit == 4) fa_merge<4><<<mgrid, 256, 0, stream>>>(Opart, mlbuf, out);
    else if (nsplit == 2) fa_merge<2><<<mgrid, 256, 0, stream>>>(Opart, mlbuf, out);
    else                  fa_merge<1><<<mgrid, 256, 0, stream>>>(Opart, mlbuf, out);
}